// Round 1
// baseline (123.844 us; speedup 1.0000x reference)
//
#include <hip/hip_runtime.h>
#include <hip/hip_bf16.h>
#include <stdint.h>

// Problem constants
#define Bb  2
#define Ss  2048
#define Hh  768
#define NHh 12
#define HDd 64

typedef short bf16x8 __attribute__((ext_vector_type(8)));
typedef float f32x4  __attribute__((ext_vector_type(4)));

// f32 -> bf16 round-to-nearest-even (bit trick; no NaN inputs expected)
__device__ __forceinline__ unsigned short f2bf(float x) {
    union { float f; unsigned int u; } v; v.f = x;
    unsigned int r = v.u + 0x7fffu + ((v.u >> 16) & 1u);
    return (unsigned short)(r >> 16);
}

// ---------------------------------------------------------------------------
// Projection: Out[m,n] = sum_k hs[m,k] * W[n,k] + bias[n], stored as bf16.
// M=4096 (B*S), N=768, K=768. Tile 128x128, BK=64, 256 threads = 4 waves,
// each wave computes a 64x64 sub-tile as 4x4 fragments of 16x16 via
// mfma_f32_16x16x32_bf16. f32 inputs are converted to bf16 while staging.
// ---------------------------------------------------------------------------
__global__ __launch_bounds__(256)
void proj_kernel(const float* __restrict__ hs,
                 const float* __restrict__ Wq, const float* __restrict__ bq,
                 const float* __restrict__ Wk, const float* __restrict__ bk,
                 unsigned short* __restrict__ Qb, unsigned short* __restrict__ Kb)
{
    const int zq = blockIdx.z;                 // 0 => Q, 1 => K
    const float* __restrict__ W    = zq ? Wk : Wq;
    const float* __restrict__ bias = zq ? bk : bq;
    unsigned short* __restrict__ Out = zq ? Kb : Qb;

    const int m0 = blockIdx.x * 128;
    const int n0 = blockIdx.y * 128;

    __shared__ unsigned short As[128 * 64];    // [row][k] bf16
    __shared__ unsigned short Bs[128 * 64];

    const int tid  = threadIdx.x;
    const int lane = tid & 63;
    const int w    = tid >> 6;                 // wave 0..3
    const int wm   = (w >> 1) * 64;            // wave sub-tile origin
    const int wn   = (w & 1) * 64;
    const int lg   = lane >> 4;                // 16-lane group 0..3
    const int l15  = lane & 15;

    f32x4 acc[4][4] = {};

    for (int k0 = 0; k0 < 768; k0 += 64) {
        // ---- stage A (hs rows) and B (W rows), f32 -> bf16 ----
        #pragma unroll
        for (int i = 0; i < 4; ++i) {
            int c   = i * 256 + tid;           // chunk of 8 elements
            int row = c >> 3, seg = (c & 7) * 8;
            const float* ga = hs + (size_t)(m0 + row) * Hh + k0 + seg;
            const float* gb = W  + (size_t)(n0 + row) * Hh + k0 + seg;
            float4 a0 = *(const float4*)ga, a1 = *(const float4*)(ga + 4);
            float4 b0 = *(const float4*)gb, b1 = *(const float4*)(gb + 4);
            bf16x8 va, vb;
            va[0] = (short)f2bf(a0.x); va[1] = (short)f2bf(a0.y);
            va[2] = (short)f2bf(a0.z); va[3] = (short)f2bf(a0.w);
            va[4] = (short)f2bf(a1.x); va[5] = (short)f2bf(a1.y);
            va[6] = (short)f2bf(a1.z); va[7] = (short)f2bf(a1.w);
            vb[0] = (short)f2bf(b0.x); vb[1] = (short)f2bf(b0.y);
            vb[2] = (short)f2bf(b0.z); vb[3] = (short)f2bf(b0.w);
            vb[4] = (short)f2bf(b1.x); vb[5] = (short)f2bf(b1.y);
            vb[6] = (short)f2bf(b1.z); vb[7] = (short)f2bf(b1.w);
            *(bf16x8*)&As[row * 64 + seg] = va;
            *(bf16x8*)&Bs[row * 64 + seg] = vb;
        }
        __syncthreads();

        // ---- MFMA over BK=64 (two k=32 steps) ----
        #pragma unroll
        for (int kk = 0; kk < 2; ++kk) {
            const int kof = kk * 32 + lg * 8;
            bf16x8 af[4], bfr[4];
            #pragma unroll
            for (int m = 0; m < 4; ++m)
                af[m] = *(bf16x8*)&As[(wm + m * 16 + l15) * 64 + kof];
            #pragma unroll
            for (int n = 0; n < 4; ++n)
                bfr[n] = *(bf16x8*)&Bs[(wn + n * 16 + l15) * 64 + kof];
            #pragma unroll
            for (int m = 0; m < 4; ++m)
                #pragma unroll
                for (int n = 0; n < 4; ++n)
                    acc[m][n] = __builtin_amdgcn_mfma_f32_16x16x32_bf16(
                        af[m], bfr[n], acc[m][n], 0, 0, 0);
        }
        __syncthreads();
    }

    // ---- epilogue: bias add, bf16 store ----
    #pragma unroll
    for (int m = 0; m < 4; ++m) {
        const int rbase = m0 + wm + m * 16 + lg * 4;
        #pragma unroll
        for (int n = 0; n < 4; ++n) {
            const int gcol = n0 + wn + n * 16 + l15;
            const float bv = bias[gcol];
            #pragma unroll
            for (int j = 0; j < 4; ++j)
                Out[(size_t)(rbase + j) * Hh + gcol] = f2bf(acc[m][n][j] + bv);
        }
    }
}

// ---------------------------------------------------------------------------
// Scores: out[b,q,h,k] = relu( (Q_h[q,:] . K_h[k,:]) / 8 + mask[b,q] )
// Per block: one (b,h) pair, 128x128 output tile. K-reduction = HD = 64.
// ---------------------------------------------------------------------------
__global__ __launch_bounds__(256)
void score_kernel(const unsigned short* __restrict__ Qb,
                  const unsigned short* __restrict__ Kb,
                  const float* __restrict__ mask,
                  float* __restrict__ out)
{
    const int q0  = blockIdx.x * 128;
    const int c0  = blockIdx.y * 128;          // key-tile origin
    const int bh  = blockIdx.z;                // b*NH + h
    const int b   = bh / NHh, h = bh % NHh;

    __shared__ unsigned short Qs[128 * 64];
    __shared__ unsigned short Ks[128 * 64];

    const int tid  = threadIdx.x;
    const int lane = tid & 63;
    const int w    = tid >> 6;
    const int wm   = (w >> 1) * 64;
    const int wn   = (w & 1) * 64;
    const int lg   = lane >> 4;
    const int l15  = lane & 15;

    // ---- stage Q and K tiles (already bf16), 16B chunks ----
    #pragma unroll
    for (int i = 0; i < 4; ++i) {
        int c   = i * 256 + tid;
        int row = c >> 3, seg = (c & 7) * 8;
        const uint4* gq = (const uint4*)(Qb + (size_t)(b * Ss + q0 + row) * Hh + h * HDd + seg);
        const uint4* gk = (const uint4*)(Kb + (size_t)(b * Ss + c0 + row) * Hh + h * HDd + seg);
        *(uint4*)&Qs[row * 64 + seg] = *gq;
        *(uint4*)&Ks[row * 64 + seg] = *gk;
    }
    __syncthreads();

    f32x4 acc[4][4] = {};
    #pragma unroll
    for (int kk = 0; kk < 2; ++kk) {
        const int kof = kk * 32 + lg * 8;
        bf16x8 af[4], bfr[4];
        #pragma unroll
        for (int m = 0; m < 4; ++m)
            af[m] = *(bf16x8*)&Qs[(wm + m * 16 + l15) * 64 + kof];
        #pragma unroll
        for (int n = 0; n < 4; ++n)
            bfr[n] = *(bf16x8*)&Ks[(wn + n * 16 + l15) * 64 + kof];
        #pragma unroll
        for (int m = 0; m < 4; ++m)
            #pragma unroll
            for (int n = 0; n < 4; ++n)
                acc[m][n] = __builtin_amdgcn_mfma_f32_16x16x32_bf16(
                    af[m], bfr[n], acc[m][n], 0, 0, 0);
    }

    // ---- epilogue: scale, mask (query axis), relu, f32 store ----
    #pragma unroll
    for (int m = 0; m < 4; ++m) {
        #pragma unroll
        for (int j = 0; j < 4; ++j) {
            const int grow = q0 + wm + m * 16 + lg * 4 + j;
            const float mv = mask[b * Ss + grow];
            #pragma unroll
            for (int n = 0; n < 4; ++n) {
                const int gcol = c0 + wn + n * 16 + l15;
                float v = acc[m][n][j] * 0.125f + mv;
                v = v > 0.f ? v : 0.f;
                out[(((size_t)b * Ss + grow) * NHh + h) * Ss + gcol] = v;
            }
        }
    }
}

// ---------------------------------------------------------------------------
extern "C" void kernel_launch(void* const* d_in, const int* in_sizes, int n_in,
                              void* d_out, int out_size, void* d_ws, size_t ws_size,
                              hipStream_t stream) {
    const float* hs   = (const float*)d_in[0];
    const float* mask = (const float*)d_in[1];
    // d_in[2] = input_ids (unused), d_in[3] = ngram (unused)
    const float* Wq = (const float*)d_in[4];
    const float* bq = (const float*)d_in[5];
    const float* Wk = (const float*)d_in[6];
    const float* bk = (const float*)d_in[7];
    float* out = (float*)d_out;

    // Workspace: bf16 Q and K, each [B*S, H] = 4096*768
    unsigned short* Qb = (unsigned short*)d_ws;
    unsigned short* Kb = Qb + (size_t)(Bb * Ss) * Hh;

    // Projections: grid = (M/128, N/128, {Q,K})
    proj_kernel<<<dim3(32, 6, 2), 256, 0, stream>>>(hs, Wq, bq, Wk, bk, Qb, Kb);

    // Scores: grid = (S/128 qtiles, S/128 ktiles, B*NH)
    score_kernel<<<dim3(16, 16, 24), 256, 0, stream>>>(Qb, Kb, mask, out);
}

// Round 2
// 118.005 us; speedup vs baseline: 1.0495x; 1.0495x over previous
//
#include <hip/hip_runtime.h>
#include <hip/hip_bf16.h>
#include <stdint.h>

// Problem constants
#define Bb  2
#define Ss  2048
#define Hh  768
#define NHh 12
#define HDd 64

typedef short bf16x8 __attribute__((ext_vector_type(8)));
typedef float f32x4  __attribute__((ext_vector_type(4)));
typedef unsigned short u16x4 __attribute__((ext_vector_type(4)));

// f32 -> bf16 round-to-nearest-even
__device__ __forceinline__ unsigned short f2bf(float x) {
    union { float f; unsigned int u; } v; v.f = x;
    unsigned int r = v.u + 0x7fffu + ((v.u >> 16) & 1u);
    return (unsigned short)(r >> 16);
}

// async global->LDS, 16B per lane (dest must be wave-uniform base + lane*16)
__device__ __forceinline__ void gl_lds16(const unsigned short* g, unsigned short* l) {
    __builtin_amdgcn_global_load_lds(
        (const __attribute__((address_space(1))) unsigned int*)g,
        (__attribute__((address_space(3))) unsigned int*)l, 16, 0, 0);
}

// ---------------------------------------------------------------------------
// Cast hs [4096x768], Wq [768x768], Wk [768x768] f32 -> bf16.
// One 8-element chunk per thread. hs: 393216 chunks, Wq/Wk: 73728 each.
// ---------------------------------------------------------------------------
__global__ __launch_bounds__(256)
void cast_kernel(const float* __restrict__ hs, const float* __restrict__ Wq,
                 const float* __restrict__ Wk,
                 unsigned short* __restrict__ hsb, unsigned short* __restrict__ Wqb,
                 unsigned short* __restrict__ Wkb)
{
    int cid = blockIdx.x * 256 + threadIdx.x;      // 0 .. 540671
    const float* src; unsigned short* dst; int base;
    if (cid < 393216)      { src = hs; dst = hsb; base = cid; }
    else if (cid < 466944) { src = Wq; dst = Wqb; base = cid - 393216; }
    else                   { src = Wk; dst = Wkb; base = cid - 466944; }
    float4 a0 = ((const float4*)src)[(size_t)base * 2];
    float4 a1 = ((const float4*)src)[(size_t)base * 2 + 1];
    bf16x8 v;
    v[0] = (short)f2bf(a0.x); v[1] = (short)f2bf(a0.y);
    v[2] = (short)f2bf(a0.z); v[3] = (short)f2bf(a0.w);
    v[4] = (short)f2bf(a1.x); v[5] = (short)f2bf(a1.y);
    v[6] = (short)f2bf(a1.z); v[7] = (short)f2bf(a1.w);
    ((bf16x8*)dst)[base] = v;
}

// ---------------------------------------------------------------------------
// Projection (pure bf16): Out[m,n] = sum_k hsb[m,k]*Wb[n,k] + bias[n] (bf16).
// 128x128 tile, BK=64, 4 waves. Operands SWAPPED (A=W rows, B=hs rows) so the
// accumulator reg axis maps to output columns -> ushort4 8B stores.
// Staging via global_load_lds width=16 (linear LDS, no conversion needed).
// ---------------------------------------------------------------------------
__global__ __launch_bounds__(256)
void proj_kernel(const unsigned short* __restrict__ hsb,
                 const unsigned short* __restrict__ Wqb,
                 const unsigned short* __restrict__ Wkb,
                 const float* __restrict__ bq, const float* __restrict__ bk,
                 unsigned short* __restrict__ Qb, unsigned short* __restrict__ Kb)
{
    const int zq = blockIdx.z;
    const unsigned short* __restrict__ Wb = zq ? Wkb : Wqb;
    const float* __restrict__ bias = zq ? bk : bq;
    unsigned short* __restrict__ Out = zq ? Kb : Qb;

    const int m0 = blockIdx.x * 128;               // hs-row tile (output rows)
    const int n0 = blockIdx.y * 128;               // W-row tile (output cols)

    __shared__ unsigned short As[128 * 64];        // hs rows  [row][k]
    __shared__ unsigned short Bs[128 * 64];        // W rows   [row][k]

    const int tid  = threadIdx.x;
    const int lane = tid & 63;
    const int w    = tid >> 6;
    const int wm   = (w >> 1) * 64;                // W-side sub-tile (out cols)
    const int wn   = (w & 1) * 64;                 // hs-side sub-tile (out rows)
    const int lg   = lane >> 4;
    const int l15  = lane & 15;

    f32x4 acc[4][4] = {};

    for (int k0 = 0; k0 < Hh; k0 += 64) {
        #pragma unroll
        for (int i = 0; i < 4; ++i) {
            int cc  = i * 256 + tid;               // 16B chunk id
            int row = cc >> 3, seg = (cc & 7) * 8;
            gl_lds16(hsb + (size_t)(m0 + row) * Hh + k0 + seg, &As[cc * 8]);
            gl_lds16(Wb  + (size_t)(n0 + row) * Hh + k0 + seg, &Bs[cc * 8]);
        }
        __syncthreads();

        #pragma unroll
        for (int kk = 0; kk < 2; ++kk) {
            const int kof = kk * 32 + lg * 8;
            bf16x8 wf[4], hf[4];
            #pragma unroll
            for (int i = 0; i < 4; ++i)
                wf[i] = *(bf16x8*)&Bs[(wm + i * 16 + l15) * 64 + kof];
            #pragma unroll
            for (int j = 0; j < 4; ++j)
                hf[j] = *(bf16x8*)&As[(wn + j * 16 + l15) * 64 + kof];
            #pragma unroll
            for (int i = 0; i < 4; ++i)
                #pragma unroll
                for (int j = 0; j < 4; ++j)
                    acc[i][j] = __builtin_amdgcn_mfma_f32_16x16x32_bf16(
                        wf[i], hf[j], acc[i][j], 0, 0, 0);
        }
        __syncthreads();
    }

    // Epilogue: reg axis = 4 consecutive output columns -> ushort4 store.
    #pragma unroll
    for (int i = 0; i < 4; ++i) {
        const int nb = n0 + wm + i * 16 + lg * 4;
        const float4 bv = *(const float4*)&bias[nb];
        #pragma unroll
        for (int j = 0; j < 4; ++j) {
            const int m = m0 + wn + j * 16 + l15;
            u16x4 o;
            o[0] = f2bf(acc[i][j][0] + bv.x);
            o[1] = f2bf(acc[i][j][1] + bv.y);
            o[2] = f2bf(acc[i][j][2] + bv.z);
            o[3] = f2bf(acc[i][j][3] + bv.w);
            *(u16x4*)&Out[(size_t)m * Hh + nb] = o;
        }
    }
}

// ---------------------------------------------------------------------------
// Scores: out[b,q,h,k] = relu( (Q_h[q,:].K_h[k,:]) / 8 + mask[b,q] )
// Operands SWAPPED (A=K rows, B=Q rows) so reg axis = 4 consecutive k
// -> float4 16B stores. Staging via global_load_lds.
// ---------------------------------------------------------------------------
__global__ __launch_bounds__(256)
void score_kernel(const unsigned short* __restrict__ Qb,
                  const unsigned short* __restrict__ Kb,
                  const float* __restrict__ mask,
                  float* __restrict__ out)
{
    const int q0 = blockIdx.x * 128;
    const int c0 = blockIdx.y * 128;               // key-tile origin
    const int bh = blockIdx.z;
    const int b  = bh / NHh, h = bh % NHh;

    __shared__ unsigned short Qs[128 * 64];
    __shared__ unsigned short Ks[128 * 64];

    const int tid  = threadIdx.x;
    const int lane = tid & 63;
    const int w    = tid >> 6;
    const int wm   = (w >> 1) * 64;                // K-side (out cols)
    const int wn   = (w & 1) * 64;                 // Q-side (out rows)
    const int lg   = lane >> 4;
    const int l15  = lane & 15;

    #pragma unroll
    for (int i = 0; i < 4; ++i) {
        int cc  = i * 256 + tid;
        int row = cc >> 3, seg = (cc & 7) * 8;
        gl_lds16(Qb + (size_t)(b * Ss + q0 + row) * Hh + h * HDd + seg, &Qs[cc * 8]);
        gl_lds16(Kb + (size_t)(b * Ss + c0 + row) * Hh + h * HDd + seg, &Ks[cc * 8]);
    }
    __syncthreads();

    f32x4 acc[4][4] = {};
    #pragma unroll
    for (int kk = 0; kk < 2; ++kk) {
        const int kof = kk * 32 + lg * 8;
        bf16x8 kf[4], qf[4];
        #pragma unroll
        for (int m = 0; m < 4; ++m)
            kf[m] = *(bf16x8*)&Ks[(wm + m * 16 + l15) * 64 + kof];
        #pragma unroll
        for (int n = 0; n < 4; ++n)
            qf[n] = *(bf16x8*)&Qs[(wn + n * 16 + l15) * 64 + kof];
        #pragma unroll
        for (int m = 0; m < 4; ++m)
            #pragma unroll
            for (int n = 0; n < 4; ++n)
                acc[m][n] = __builtin_amdgcn_mfma_f32_16x16x32_bf16(
                    kf[m], qf[n], acc[m][n], 0, 0, 0);
    }

    // Epilogue: per (n) the query row q; per (m) a float4 of 4 consecutive k.
    #pragma unroll
    for (int n = 0; n < 4; ++n) {
        const int q = q0 + wn + n * 16 + l15;
        const float mv = mask[b * Ss + q];
        float* orow = out + ((size_t)(b * Ss + q) * NHh + h) * Ss;
        #pragma unroll
        for (int m = 0; m < 4; ++m) {
            const int kb = c0 + wm + m * 16 + lg * 4;
            float4 o;
            float v0 = acc[m][n][0] * 0.125f + mv;
            float v1 = acc[m][n][1] * 0.125f + mv;
            float v2 = acc[m][n][2] * 0.125f + mv;
            float v3 = acc[m][n][3] * 0.125f + mv;
            o.x = v0 > 0.f ? v0 : 0.f;
            o.y = v1 > 0.f ? v1 : 0.f;
            o.z = v2 > 0.f ? v2 : 0.f;
            o.w = v3 > 0.f ? v3 : 0.f;
            *(float4*)&orow[kb] = o;
        }
    }
}

// ---------------------------------------------------------------------------
extern "C" void kernel_launch(void* const* d_in, const int* in_sizes, int n_in,
                              void* d_out, int out_size, void* d_ws, size_t ws_size,
                              hipStream_t stream) {
    const float* hs   = (const float*)d_in[0];
    const float* mask = (const float*)d_in[1];
    // d_in[2] = input_ids (unused), d_in[3] = ngram (unused)
    const float* Wq = (const float*)d_in[4];
    const float* bq = (const float*)d_in[5];
    const float* Wk = (const float*)d_in[6];
    const float* bk = (const float*)d_in[7];
    float* out = (float*)d_out;

    // Workspace layout (bf16 elements):
    unsigned short* Qb  = (unsigned short*)d_ws;   // 4096*768
    unsigned short* Kb  = Qb  + 3145728;
    unsigned short* hsb = Kb  + 3145728;
    unsigned short* Wqb = hsb + 3145728;           // 768*768
    unsigned short* Wkb = Wqb + 589824;

    cast_kernel<<<2112, 256, 0, stream>>>(hs, Wq, Wk, hsb, Wqb, Wkb);
    proj_kernel<<<dim3(32, 6, 2), 256, 0, stream>>>(hsb, Wqb, Wkb, bq, bk, Qb, Kb);
    score_kernel<<<dim3(16, 16, 24), 256, 0, stream>>>(Qb, Kb, mask, out);
}